// Round 2
// baseline (790.761 us; speedup 1.0000x reference)
//
#include <hip/hip_runtime.h>
#include <hip/hip_bf16.h>
#include <math.h>

#define Ntok 8192
#define Dm   1024
#define Hm   2048
#define NE   8

typedef __hip_bfloat16 bf16;
typedef __attribute__((ext_vector_type(8))) short short8;
typedef __attribute__((ext_vector_type(4))) float f32x4;

static __device__ __forceinline__ float b2f(bf16 v){ return __bfloat162float(v); }
static __device__ __forceinline__ bf16  f2b(float v){ return __float2bfloat16(v); }

// async global->LDS, 16B per lane; LDS dest is wave-uniform base (lane i lands at base + i*16)
static __device__ __forceinline__ void gl2lds16(const bf16* g, bf16* l) {
    __builtin_amdgcn_global_load_lds(
        (const __attribute__((address_space(1))) unsigned*)(const void*)g,
        (__attribute__((address_space(3))) unsigned*)(void*)l, 16, 0, 0);
}

// ---------------- dtype detect ----------------
__global__ void detect_kernel(const unsigned* __restrict__ xw, int* dtf)
{
    unsigned w = xw[threadIdx.x];
    int ex = (w >> 23) & 0xff;
    unsigned long long m = __ballot(ex < 200);
    if (threadIdx.x == 0) *dtf = (__popcll(m) > 32) ? 1 : 0;
}

// ---------------- x -> bf16 (xb lives in d_out scratch; dead before combine rewrites y) ----------------
__global__ void xconv_kernel(const void* __restrict__ xv, const int* __restrict__ dtf,
                             bf16* __restrict__ xb)
{
    int gid = blockIdx.x * 256 + threadIdx.x;
    size_t i = (size_t)gid * 8;
    if (*dtf) {
        const float* x = (const float*)xv + i;
        float4 v0 = *(const float4*)x;
        float4 v1 = *(const float4*)(x + 4);
        bf16 t[8] = { f2b(v0.x), f2b(v0.y), f2b(v0.z), f2b(v0.w),
                      f2b(v1.x), f2b(v1.y), f2b(v1.z), f2b(v1.w) };
        *(uint4*)(xb + i) = *(uint4*)t;
    } else {
        *(uint4*)(xb + i) = *(const uint4*)((const bf16*)xv + i);
    }
}

// ---------------- gate: softmax + top-2 routing ----------------
__global__ void gate_kernel(const void* __restrict__ xv, const void* __restrict__ wgv,
                            const int* __restrict__ dtf,
                            int* cnt, float* Psum, float* wts, int* idx_buf)
{
    int fp32 = *dtf;
    int lane = threadIdx.x & 63;
    int wv   = threadIdx.x >> 6;
    int n    = blockIdx.x * 4 + wv;

    float acc[NE];
    #pragma unroll
    for (int e = 0; e < NE; e++) acc[e] = 0.f;

    if (fp32) {
        const float* xr = (const float*)xv + (size_t)n * Dm;
        const float* Wg = (const float*)wgv;
        #pragma unroll
        for (int i = 0; i < 16; i++) {
            float xval = xr[lane + 64*i];
            #pragma unroll
            for (int e = 0; e < NE; e++) acc[e] += xval * Wg[e*Dm + lane + 64*i];
        }
    } else {
        const bf16* xr = (const bf16*)xv + (size_t)n * Dm;
        const bf16* Wg = (const bf16*)wgv;
        #pragma unroll
        for (int i = 0; i < 16; i++) {
            float xval = b2f(xr[lane + 64*i]);
            #pragma unroll
            for (int e = 0; e < NE; e++) acc[e] += xval * b2f(Wg[e*Dm + lane + 64*i]);
        }
    }
    #pragma unroll
    for (int e = 0; e < NE; e++) {
        float v = acc[e];
        #pragma unroll
        for (int off = 32; off > 0; off >>= 1) v += __shfl_xor(v, off);
        acc[e] = v;
    }
    float mx = acc[0];
    #pragma unroll
    for (int e = 1; e < NE; e++) mx = fmaxf(mx, acc[e]);
    float p[NE]; float s = 0.f;
    #pragma unroll
    for (int e = 0; e < NE; e++) { p[e] = expf(acc[e] - mx); s += p[e]; }
    float inv = 1.f / s;
    #pragma unroll
    for (int e = 0; e < NE; e++) p[e] *= inv;
    int e0 = 0;
    #pragma unroll
    for (int e = 1; e < NE; e++) if (p[e] > p[e0]) e0 = e;
    int e1 = (e0 == 0) ? 1 : 0;
    #pragma unroll
    for (int e = 0; e < NE; e++) if (e != e0 && p[e] > p[e1]) e1 = e;

    if (lane < NE) atomicAdd(Psum + lane, p[lane]);
    if (lane == 0) {
        int p0 = atomicAdd(cnt + e0, 1);
        idx_buf[e0*Ntok + p0] = n;              // k=0
        int p1 = atomicAdd(cnt + e1, 1);
        idx_buf[e1*Ntok + p1] = n | 0x10000;    // k=1 flag in bit 16
        wts[2*n]   = p[e0];
        wts[2*n+1] = p[e1];
    }
}

// ---------------- aux loss + per-expert dense-slot offsets ----------------
__global__ void aux_kernel(const int* __restrict__ cnt, const float* __restrict__ Psum,
                           const int* __restrict__ dtf, int* __restrict__ offs,
                           void* __restrict__ out)
{
    if (threadIdx.x == 0) {
        float s = 0.f; int a = 0;
        for (int e = 0; e < NE; e++) {
            offs[e] = a; a += cnt[e];
            s += (float)cnt[e] * Psum[e];
        }
        float aux = 0.08f * s / (16384.f * 8192.f);
        if (*dtf) ((float*)out)[(size_t)Ntok * Dm] = aux;
        else      ((bf16*)out)[(size_t)Ntok * Dm] = f2b(aux);
    }
}

// ---------------- transpose (two sources, same shape): src[R][C] -> dst[C][R] bf16, 64x64 tiles ----------------
__global__ void transpose2_kernel(const void* __restrict__ sA, const void* __restrict__ sB,
                                  bf16* __restrict__ dA, bf16* __restrict__ dB,
                                  int R, int C, const int* __restrict__ dtf)
{
    __shared__ bf16 t[64][68];
    int mat = blockIdx.z >> 3, e = blockIdx.z & 7;
    const void* src = mat ? sB : sA;
    bf16* dst = mat ? dB : dA;
    size_t base = (size_t)e * R * C;
    int c0 = blockIdx.x * 64, r0 = blockIdx.y * 64;
    int tid = threadIdx.x;
    int lr = tid >> 4;            // 0..15
    int lc = (tid & 15) * 4;      // 0..60

    if (*dtf) {
        const float* s = (const float*)src + base;
        #pragma unroll
        for (int i = 0; i < 4; i++) {
            float4 v = *(const float4*)(s + (size_t)(r0 + lr + 16*i) * C + c0 + lc);
            t[lr+16*i][lc+0] = f2b(v.x); t[lr+16*i][lc+1] = f2b(v.y);
            t[lr+16*i][lc+2] = f2b(v.z); t[lr+16*i][lc+3] = f2b(v.w);
        }
    } else {
        const bf16* s = (const bf16*)src + base;
        #pragma unroll
        for (int i = 0; i < 4; i++) {
            bf16 v[4];
            *(uint2*)v = *(const uint2*)(s + (size_t)(r0 + lr + 16*i) * C + c0 + lc);
            t[lr+16*i][lc+0] = v[0]; t[lr+16*i][lc+1] = v[1];
            t[lr+16*i][lc+2] = v[2]; t[lr+16*i][lc+3] = v[3];
        }
    }
    __syncthreads();
    int oc = tid >> 2;            // 0..63
    int os = tid & 3;             // 16-element segment
    bf16 ov[16];
    #pragma unroll
    for (int j = 0; j < 16; j++) ov[j] = t[os*16 + j][oc];
    bf16* dp = dst + base + (size_t)(c0 + oc) * R + r0 + os*16;
    *(uint4*)dp       = *(uint4*)ov;
    *(uint4*)(dp + 8) = *(uint4*)(ov + 8);
}

// =====================================================================================
// 8-phase pipelined FFN GEMM (T2 swizzle + T3/T4 counted-vmcnt + T5 setprio).
// MODE 0 (ffn1): A = gathered xb tokens, B = interleaved W1t/W3t, epi = silu pair -> hbuf
// MODE 1 (ffn2): A = dense hbuf slots,   B = W2t,                 epi = bias -> scatter outs
// Tile: 256 rows x 256 B-rows, BK=64, 512 threads (8 waves, 2Mx4N), per-wave 128x64.
// LDS: 2 dbuf x {A,B} x 2 half x [128][64] bf16 = 128 KiB. Swizzle: chunk ^= (row&7)
// applied on read; inverse applied to per-lane GLOBAL source (gl2lds dest stays linear).
// Per K-tile (4 phases): reads q0:A0+B0(12), q1:B1(4), q2:A1(8), q3:B0 re-read(4).
// Staging order (into buf^1): q0->A0, q1->B0, q2->B1, q3->A1. vmcnt(4) at q0/q1/q3 ends.
// =====================================================================================

#define BAR()  { asm volatile("" ::: "memory"); __builtin_amdgcn_s_barrier(); asm volatile("" ::: "memory"); }
#define VMW4() asm volatile("s_waitcnt vmcnt(4)" ::: "memory")
#define VMW2() asm volatile("s_waitcnt vmcnt(2)" ::: "memory")
#define VMW0() asm volatile("s_waitcnt vmcnt(0)" ::: "memory")

#define LOADA(_bf, _mh) do { \
    int _ab = ((_bf)*4 + (_mh))*8192 + (wr*64 + mrow)*64; \
    _Pragma("unroll") \
    for (int _m = 0; _m < 4; _m++) { \
      _Pragma("unroll") \
      for (int _k = 0; _k < 2; _k++) \
        af[_m][_k] = *(const short8*)&smem[_ab + _m*1024 + kxo[_k]]; \
    } } while(0)

#define LOADB(_bf, _nh) do { \
    int _bb = ((_bf)*4 + 2 + (_nh))*8192 + (wc*32 + mrow)*64; \
    _Pragma("unroll") \
    for (int _n = 0; _n < 2; _n++) { \
      _Pragma("unroll") \
      for (int _k = 0; _k < 2; _k++) \
        bfr[_n][_k] = *(const short8*)&smem[_bb + _n*1024 + kxo[_k]]; \
    } } while(0)

#define MFMAQ(_mh, _nh) do { \
    _Pragma("unroll") \
    for (int _m = 0; _m < 4; _m++) \
      _Pragma("unroll") \
      for (int _n = 0; _n < 2; _n++) \
        _Pragma("unroll") \
        for (int _k = 0; _k < 2; _k++) \
          acc[(_mh)*4+_m][(_nh)*2+_n] = __builtin_amdgcn_mfma_f32_16x16x32_bf16( \
              af[_m][_k], bfr[_n][_k], acc[(_mh)*4+_m][(_nh)*2+_n], 0, 0, 0); \
    } while(0)

#define STAGE_A0(_nb) do { gl2lds16(pA00, &smem[((_nb)*4+0)*8192 + w*512]); \
                           gl2lds16(pA01, &smem[((_nb)*4+0)*8192 + 4096 + w*512]); \
                           pA00 += 64; pA01 += 64; } while(0)
#define STAGE_A1(_nb) do { gl2lds16(pA10, &smem[((_nb)*4+1)*8192 + w*512]); \
                           gl2lds16(pA11, &smem[((_nb)*4+1)*8192 + 4096 + w*512]); \
                           pA10 += 64; pA11 += 64; } while(0)
#define STAGE_B0(_nb) do { gl2lds16(pB00, &smem[((_nb)*4+2)*8192 + w*512]); \
                           gl2lds16(pB01, &smem[((_nb)*4+2)*8192 + 4096 + w*512]); \
                           pB00 += 64; pB01 += 64; } while(0)
#define STAGE_B1(_nb) do { gl2lds16(pB10, &smem[((_nb)*4+3)*8192 + w*512]); \
                           gl2lds16(pB11, &smem[((_nb)*4+3)*8192 + 4096 + w*512]); \
                           pB10 += 64; pB11 += 64; } while(0)

template<int MODE>
__global__ __launch_bounds__(512) void ffn_kernel(
    const bf16* __restrict__ Asrc,   // xb (MODE0) / hbuf (MODE1)
    const bf16* __restrict__ Bsrc1,  // w1t / w2t
    const bf16* __restrict__ Bsrc3,  // w3t / (unused)
    const void* __restrict__ bv1,    // b1 / b2
    const void* __restrict__ bv3,    // b3 / (unused)
    const int* __restrict__ dtf,
    const int* __restrict__ cnt, const int* __restrict__ offs,
    const int* __restrict__ idx_buf,
    bf16* __restrict__ Out)          // hbuf / outs
{
    const int KD = MODE ? Hm : Dm;
    const int NT = KD / 64;
    int e = blockIdx.z;
    int c = cnt[e];
    int m0 = blockIdx.y * 256;
    if (m0 >= c) return;
    int n0 = blockIdx.x * (MODE ? 256 : 128);
    int fp32 = *dtf;
    int slot0 = offs[e] + m0;

    __shared__ __align__(16) bf16 smem[65536];   // 128 KiB: [buf2][op2][half2][128][64]
    __shared__ int tk[256];

    int tid = threadIdx.x;
    int cm = c - 1 - m0; if (cm > 255) cm = 255;
    if (tid < 256) {
        int r = tid > cm ? cm : tid;
        int v = idx_buf[e*Ntok + m0 + r];
        tk[tid] = MODE ? (2*(v & 0xffff) + (v >> 16)) : (v & 0xffff);
    }
    __syncthreads();

    int lane = tid & 63, w = tid >> 6;
    int wr = w >> 2, wc = w & 3;
    int mrow = lane & 15, kg = lane >> 4;
    int flip = mrow & 7;
    int kxo[2];
    kxo[0] = ((0*4 + kg) ^ flip) * 8;
    kxo[1] = ((1*4 + kg) ^ flip) * 8;

    // staging geometry: thread covers rows {rs, 64+rs} of each half; 16B chunk cs_src
    int rs = tid >> 3;                       // 0..63
    int cs_src = (tid & 7) ^ (rs & 7);       // inverse swizzle on global source

    const bf16 *pA00, *pA01, *pA10, *pA11, *pB00, *pB01, *pB10, *pB11;
    {
        // A rows: half h, issue l -> tile row h*128 + l*64 + rs
        int r00 = rs, r01 = 64 + rs, r10 = 128 + rs, r11 = 192 + rs;
        if (MODE == 0) {
            pA00 = Asrc + (size_t)tk[r00] * Dm + cs_src*8;
            pA01 = Asrc + (size_t)tk[r01] * Dm + cs_src*8;
            pA10 = Asrc + (size_t)tk[r10] * Dm + cs_src*8;
            pA11 = Asrc + (size_t)tk[r11] * Dm + cs_src*8;
        } else {
            int c00 = r00 > cm ? cm : r00, c01 = r01 > cm ? cm : r01;
            int c10 = r10 > cm ? cm : r10, c11 = r11 > cm ? cm : r11;
            pA00 = Asrc + (size_t)(slot0 + c00) * Hm + cs_src*8;
            pA01 = Asrc + (size_t)(slot0 + c01) * Hm + cs_src*8;
            pA10 = Asrc + (size_t)(slot0 + c10) * Hm + cs_src*8;
            pA11 = Asrc + (size_t)(slot0 + c11) * Hm + cs_src*8;
        }
        if (MODE == 0) {
            // B-row r: matrix = (r>>4)&1, h = n0 + (r>>7)*64 + ((r>>5)&3)*16 + (r&15)
            #pragma unroll
            for (int hl = 0; hl < 4; hl++) {
                int r = hl*64 + rs;
                int matb = (r >> 4) & 1;
                int hcol = n0 + (r >> 7)*64 + ((r >> 5) & 3)*16 + (r & 15);
                const bf16* base = (matb ? Bsrc3 : Bsrc1) + (size_t)e*Hm*Dm
                                 + (size_t)hcol * Dm + cs_src*8;
                if (hl == 0) pB00 = base; else if (hl == 1) pB01 = base;
                else if (hl == 2) pB10 = base; else pB11 = base;
            }
        } else {
            pB00 = Bsrc1 + (size_t)e*Dm*Hm + (size_t)(n0 + rs      ) * Hm + cs_src*8;
            pB01 = Bsrc1 + (size_t)e*Dm*Hm + (size_t)(n0 + rs +  64) * Hm + cs_src*8;
            pB10 = Bsrc1 + (size_t)e*Dm*Hm + (size_t)(n0 + rs + 128) * Hm + cs_src*8;
            pB11 = Bsrc1 + (size_t)e*Dm*Hm + (size_t)(n0 + rs + 192) * Hm + cs_src*8;
        }
    }

    f32x4 acc[8][4];
    f32x4 z = {0.f, 0.f, 0.f, 0.f};
    #pragma unroll
    for (int m = 0; m < 8; m++)
        #pragma unroll
        for (int n = 0; n < 4; n++) acc[m][n] = z;

    short8 af[4][2];
    short8 bfr[2][2];

    // prologue: stage K-tile 0 into buf 0, drain, sync
    STAGE_A0(0); STAGE_B0(0); STAGE_B1(0); STAGE_A1(0);
    VMW0();
    __syncthreads();

    for (int t = 0; t < NT; ++t) {
        int buf = t & 1, nbuf = buf ^ 1;
        bool more = (t + 1 < NT);
        // ---- q0: quadrant (mh0, nh0) ----
        LOADA(buf, 0); LOADB(buf, 0);
        if (more) STAGE_A0(nbuf);
        BAR();
        __builtin_amdgcn_s_setprio(1); MFMAQ(0, 0); __builtin_amdgcn_s_setprio(0);
        if (more) VMW4(); else VMW2();
        BAR();
        // ---- q1: (mh0, nh1) — af kept, read B1 ----
        LOADB(buf, 1);
        if (more) STAGE_B0(nbuf);
        BAR();
        __builtin_amdgcn_s_setprio(1); MFMAQ(0, 1); __builtin_amdgcn_s_setprio(0);
        if (more) VMW4(); else VMW0();
        BAR();
        // ---- q2: (mh1, nh1) — bfr kept, read A1 ----
        LOADA(buf, 1);
        if (more) STAGE_B1(nbuf);
        BAR();
        __builtin_amdgcn_s_setprio(1); MFMAQ(1, 1); __builtin_amdgcn_s_setprio(0);
        BAR();
        // ---- q3: (mh1, nh0) — af kept, re-read B0 (landed long ago) ----
        LOADB(buf, 0);
        if (more) STAGE_A1(nbuf);
        BAR();
        __builtin_amdgcn_s_setprio(1); MFMAQ(1, 0); __builtin_amdgcn_s_setprio(0);
        if (more) VMW4();
        BAR();
    }

    // ---- epilogue ----
    if (MODE == 0) {
        #pragma unroll
        for (int nh = 0; nh < 2; nh++) {
            int hcol = n0 + nh*64 + wc*16 + mrow;
            float bb1 = fp32 ? ((const float*)bv1)[e*Hm + hcol] : b2f(((const bf16*)bv1)[e*Hm + hcol]);
            float bb3 = fp32 ? ((const float*)bv3)[e*Hm + hcol] : b2f(((const bf16*)bv3)[e*Hm + hcol]);
            #pragma unroll
            for (int ms = 0; ms < 8; ms++) {
                int rbase = (ms>>2)*128 + wr*64 + (ms&3)*16 + kg*4;
                #pragma unroll
                for (int j = 0; j < 4; j++) {
                    int tr = rbase + j;
                    if (m0 + tr < c) {
                        float v1 = acc[ms][nh*2+0][j] + bb1;
                        float v3 = acc[ms][nh*2+1][j] + bb3;
                        float hv = (v1 / (1.f + expf(-v1))) * v3;   // silu(v1)*v3
                        Out[(size_t)(slot0 + tr)*Hm + hcol] = f2b(hv);
                    }
                }
            }
        }
    } else {
        #pragma unroll
        for (int ns = 0; ns < 4; ns++) {
            int col = n0 + (ns>>1)*128 + wc*32 + (ns&1)*16 + mrow;
            float bb2 = fp32 ? ((const float*)bv1)[e*Dm + col] : b2f(((const bf16*)bv1)[e*Dm + col]);
            #pragma unroll
            for (int ms = 0; ms < 8; ms++) {
                int rbase = (ms>>2)*128 + wr*64 + (ms&3)*16 + kg*4;
                #pragma unroll
                for (int j = 0; j < 4; j++) {
                    int tr = rbase + j;
                    if (m0 + tr < c)
                        Out[(size_t)tk[tr]*Dm + col] = f2b(acc[ms][ns][j] + bb2);
                }
            }
        }
    }
}

#undef LOADA
#undef LOADB
#undef MFMAQ
#undef STAGE_A0
#undef STAGE_A1
#undef STAGE_B0
#undef STAGE_B1

// ---------------- combine: y[n] = w0*out[2n] + w1*out[2n+1] ----------------
__global__ void combine_kernel(const bf16* __restrict__ outs, const float* __restrict__ wts,
                               const int* __restrict__ dtf, void* __restrict__ yv)
{
    int gid = blockIdx.x * 256 + threadIdx.x;
    int n = gid >> 7;
    int j = (gid & 127) * 8;
    float w0 = wts[2*n], w1 = wts[2*n+1];
    bf16 ra[8], rb[8];
    *(uint4*)ra = *(const uint4*)(outs + (size_t)(2*n)   * Dm + j);
    *(uint4*)rb = *(const uint4*)(outs + (size_t)(2*n+1) * Dm + j);
    float o[8];
    #pragma unroll
    for (int t = 0; t < 8; t++)
        o[t] = w0 * b2f(ra[t]) + w1 * b2f(rb[t]);
    if (*dtf) {
        float* y = (float*)yv + (size_t)n * Dm + j;
        *(float4*)y       = make_float4(o[0], o[1], o[2], o[3]);
        *(float4*)(y + 4) = make_float4(o[4], o[5], o[6], o[7]);
    } else {
        bf16 ro[8];
        #pragma unroll
        for (int t = 0; t < 8; t++) ro[t] = f2b(o[t]);
        *(uint4*)((bf16*)yv + (size_t)n * Dm + j) = *(uint4*)ro;
    }
}

extern "C" void kernel_launch(void* const* d_in, const int* in_sizes, int n_in,
                              void* d_out, int out_size, void* d_ws, size_t ws_size,
                              hipStream_t stream)
{
    (void)in_sizes; (void)n_in; (void)out_size; (void)ws_size;
    const void* x  = d_in[0];
    const void* Wg = d_in[1];
    const void* W1 = d_in[2];
    const void* b1 = d_in[3];
    const void* W2 = d_in[4];
    const void* b2 = d_in[5];
    const void* W3 = d_in[6];
    const void* b3 = d_in[7];

    char* ws = (char*)d_ws;
    int*   cnt  = (int*)ws;                      // [0,32)
    int*   dtf  = (int*)(ws + 64);               // dtype flag
    float* Psum = (float*)(ws + 256);            // [256,288)
    int*   offs = (int*)(ws + 512);              // [512,544)
    float* wts  = (float*)(ws + 4096);           // 64 KB -> 69632
    int*   idx  = (int*)(ws + 69632);            // 256 KB -> 331776
    bf16* bufA  = (bf16*)(ws + 331776);          // 32 MiB (w1t, then w2t)
    bf16* bufB  = (bf16*)(ws + 33886208);        // 32 MiB (w3t, then outs)
    bf16* hbuf  = (bf16*)(ws + 67440640);        // 64 MiB
    bf16* outs  = bufB;
    bf16* xb    = (bf16*)d_out;                  // x as bf16 in d_out scratch (dead before combine)

    hipMemsetAsync(d_ws, 0, 4096, stream);
    detect_kernel<<<1, 64, 0, stream>>>((const unsigned*)x, dtf);
    xconv_kernel<<<(Ntok*Dm/8)/256, 256, 0, stream>>>(x, dtf, xb);
    gate_kernel<<<Ntok/4, 256, 0, stream>>>(x, Wg, dtf, cnt, Psum, wts, idx);
    aux_kernel<<<1, 64, 0, stream>>>(cnt, Psum, dtf, offs, d_out);
    // W1,W3: [D][H] -> [H][D]
    transpose2_kernel<<<dim3(Hm/64, Dm/64, 16), 256, 0, stream>>>(W1, W3, bufA, bufB, Dm, Hm, dtf);
    ffn_kernel<0><<<dim3(Hm/128, Ntok/256, NE), 512, 0, stream>>>(
        xb, bufA, bufB, b1, b3, dtf, cnt, offs, idx, hbuf);
    // W2: [H][D] -> [D][H]  (into bufA, w1t dead)
    transpose2_kernel<<<dim3(Dm/64, Hm/64, 8), 256, 0, stream>>>(W2, W2, bufA, bufA, Hm, Dm, dtf);
    ffn_kernel<1><<<dim3(Dm/256, Ntok/256, NE), 512, 0, stream>>>(
        hbuf, bufA, bufA, b2, b2, dtf, cnt, offs, idx, outs);
    combine_kernel<<<(Ntok*Dm/8)/256, 256, 0, stream>>>(outs, wts, dtf, d_out);
}

// Round 3
// 605.990 us; speedup vs baseline: 1.3049x; 1.3049x over previous
//
#include <hip/hip_runtime.h>
#include <hip/hip_bf16.h>
#include <math.h>

#define Ntok 8192
#define Dm   1024
#define Hm   2048
#define NE   8

typedef __hip_bfloat16 bf16;
typedef __attribute__((ext_vector_type(8))) short short8;
typedef __attribute__((ext_vector_type(4))) float f32x4;

static __device__ __forceinline__ float b2f(bf16 v){ return __bfloat162float(v); }
static __device__ __forceinline__ bf16  f2b(float v){ return __float2bfloat16(v); }

// async global->LDS, 16B per lane; LDS dest is wave-uniform base (lane i lands at base + i*16)
static __device__ __forceinline__ void gl2lds16(const bf16* g, bf16* l) {
    __builtin_amdgcn_global_load_lds(
        (const __attribute__((address_space(1))) unsigned*)(const void*)g,
        (__attribute__((address_space(3))) unsigned*)(void*)l, 16, 0, 0);
}

// ---------------- dtype detect ----------------
__global__ void detect_kernel(const unsigned* __restrict__ xw, int* dtf)
{
    unsigned w = xw[threadIdx.x];
    int ex = (w >> 23) & 0xff;
    unsigned long long m = __ballot(ex < 200);
    if (threadIdx.x == 0) *dtf = (__popcll(m) > 32) ? 1 : 0;
}

// ---------------- gate: softmax + top-2 routing + fused x->bf16 conversion ----------------
// 1024 threads = 16 waves = 16 tokens/block. Hierarchical atomics: LDS aggregation,
// then 8 global atomicAdds per block (Psum padded to 64B stride -> no cacheline storm).
__global__ __launch_bounds__(1024) void gate_kernel(
    const void* __restrict__ xv, const void* __restrict__ wgv,
    const int* __restrict__ dtf,
    int* cnt, float* Psum, float* wts, int* idx_buf, bf16* __restrict__ xb)
{
    int fp32 = *dtf;
    int tid  = threadIdx.x;
    int lane = tid & 63;
    int wv   = tid >> 6;                 // 0..15
    int n    = blockIdx.x * 16 + wv;

    __shared__ float lP[8];
    __shared__ int   lc[8];
    __shared__ int   gbase[8];
    __shared__ int   tslot[16][2];
    __shared__ int   texp[16][2];

    if (tid < 8) { lP[tid] = 0.f; lc[tid] = 0; }
    __syncthreads();

    float acc[NE];
    #pragma unroll
    for (int e = 0; e < NE; e++) acc[e] = 0.f;

    if (fp32) {
        const float* xr = (const float*)xv + (size_t)n * Dm;
        const float* Wg = (const float*)wgv;
        #pragma unroll
        for (int i = 0; i < 16; i++) {
            float xval = xr[lane + 64*i];
            xb[(size_t)n * Dm + lane + 64*i] = f2b(xval);
            #pragma unroll
            for (int e = 0; e < NE; e++) acc[e] += xval * Wg[e*Dm + lane + 64*i];
        }
    } else {
        const bf16* xr = (const bf16*)xv + (size_t)n * Dm;
        const bf16* Wg = (const bf16*)wgv;
        #pragma unroll
        for (int i = 0; i < 16; i++) {
            bf16 xraw = xr[lane + 64*i];
            xb[(size_t)n * Dm + lane + 64*i] = xraw;
            float xval = b2f(xraw);
            #pragma unroll
            for (int e = 0; e < NE; e++) acc[e] += xval * b2f(Wg[e*Dm + lane + 64*i]);
        }
    }
    #pragma unroll
    for (int e = 0; e < NE; e++) {
        float v = acc[e];
        #pragma unroll
        for (int off = 32; off > 0; off >>= 1) v += __shfl_xor(v, off);
        acc[e] = v;
    }
    float mx = acc[0];
    #pragma unroll
    for (int e = 1; e < NE; e++) mx = fmaxf(mx, acc[e]);
    float p[NE]; float s = 0.f;
    #pragma unroll
    for (int e = 0; e < NE; e++) { p[e] = expf(acc[e] - mx); s += p[e]; }
    float inv = 1.f / s;
    #pragma unroll
    for (int e = 0; e < NE; e++) p[e] *= inv;
    int e0 = 0;
    #pragma unroll
    for (int e = 1; e < NE; e++) if (p[e] > p[e0]) e0 = e;
    int e1 = (e0 == 0) ? 1 : 0;
    #pragma unroll
    for (int e = 0; e < NE; e++) if (e != e0 && p[e] > p[e1]) e1 = e;

    if (lane < NE) atomicAdd(&lP[lane], p[lane]);   // LDS atomic
    if (lane == 0) {
        tslot[wv][0] = atomicAdd(&lc[e0], 1);       // LDS atomic, local slot
        tslot[wv][1] = atomicAdd(&lc[e1], 1);
        texp[wv][0] = e0; texp[wv][1] = e1;
        wts[2*n]   = p[e0];
        wts[2*n+1] = p[e1];
    }
    __syncthreads();
    if (tid < 8) {
        gbase[tid] = atomicAdd(cnt + tid, lc[tid]);           // 8 global atomics/block
        atomicAdd(Psum + tid*16, lP[tid]);                    // 64B-strided, no line sharing
    }
    __syncthreads();
    if (lane == 0) {
        int ea = texp[wv][0], eb = texp[wv][1];
        idx_buf[ea*Ntok + gbase[ea] + tslot[wv][0]] = n;              // k=0
        idx_buf[eb*Ntok + gbase[eb] + tslot[wv][1]] = n | 0x10000;    // k=1 flag bit16
    }
}

// ---------------- aux loss + per-expert dense-slot offsets ----------------
__global__ void aux_kernel(const int* __restrict__ cnt, const float* __restrict__ Psum,
                           const int* __restrict__ dtf, int* __restrict__ offs,
                           void* __restrict__ out)
{
    if (threadIdx.x == 0) {
        float s = 0.f; int a = 0;
        for (int e = 0; e < NE; e++) {
            offs[e] = a; a += cnt[e];
            s += (float)cnt[e] * Psum[e*16];
        }
        float aux = 0.08f * s / (16384.f * 8192.f);
        if (*dtf) ((float*)out)[(size_t)Ntok * Dm] = aux;
        else      ((bf16*)out)[(size_t)Ntok * Dm] = f2b(aux);
    }
}

// ---------------- transpose (two sources, same shape): src[R][C] -> dst[C][R] bf16, 64x64 tiles ----------------
__global__ void transpose2_kernel(const void* __restrict__ sA, const void* __restrict__ sB,
                                  bf16* __restrict__ dA, bf16* __restrict__ dB,
                                  int R, int C, const int* __restrict__ dtf)
{
    __shared__ bf16 t[64][68];
    int mat = blockIdx.z >> 3, e = blockIdx.z & 7;
    const void* src = mat ? sB : sA;
    bf16* dst = mat ? dB : dA;
    size_t base = (size_t)e * R * C;
    int c0 = blockIdx.x * 64, r0 = blockIdx.y * 64;
    int tid = threadIdx.x;
    int lr = tid >> 4;            // 0..15
    int lc = (tid & 15) * 4;      // 0..60

    if (*dtf) {
        const float* s = (const float*)src + base;
        #pragma unroll
        for (int i = 0; i < 4; i++) {
            float4 v = *(const float4*)(s + (size_t)(r0 + lr + 16*i) * C + c0 + lc);
            t[lr+16*i][lc+0] = f2b(v.x); t[lr+16*i][lc+1] = f2b(v.y);
            t[lr+16*i][lc+2] = f2b(v.z); t[lr+16*i][lc+3] = f2b(v.w);
        }
    } else {
        const bf16* s = (const bf16*)src + base;
        #pragma unroll
        for (int i = 0; i < 4; i++) {
            bf16 v[4];
            *(uint2*)v = *(const uint2*)(s + (size_t)(r0 + lr + 16*i) * C + c0 + lc);
            t[lr+16*i][lc+0] = v[0]; t[lr+16*i][lc+1] = v[1];
            t[lr+16*i][lc+2] = v[2]; t[lr+16*i][lc+3] = v[3];
        }
    }
    __syncthreads();
    int oc = tid >> 2;            // 0..63
    int os = tid & 3;             // 16-element segment
    bf16 ov[16];
    #pragma unroll
    for (int j = 0; j < 16; j++) ov[j] = t[os*16 + j][oc];
    bf16* dp = dst + base + (size_t)(c0 + oc) * R + r0 + os*16;
    *(uint4*)dp       = *(uint4*)ov;
    *(uint4*)(dp + 8) = *(uint4*)(ov + 8);
}

// =====================================================================================
// 8-phase pipelined FFN GEMM (unchanged from R2 — correct, ~620-650 TF).
// =====================================================================================

#define BAR()  { asm volatile("" ::: "memory"); __builtin_amdgcn_s_barrier(); asm volatile("" ::: "memory"); }
#define VMW4() asm volatile("s_waitcnt vmcnt(4)" ::: "memory")
#define VMW2() asm volatile("s_waitcnt vmcnt(2)" ::: "memory")
#define VMW0() asm volatile("s_waitcnt vmcnt(0)" ::: "memory")

#define LOADA(_bf, _mh) do { \
    int _ab = ((_bf)*4 + (_mh))*8192 + (wr*64 + mrow)*64; \
    _Pragma("unroll") \
    for (int _m = 0; _m < 4; _m++) { \
      _Pragma("unroll") \
      for (int _k = 0; _k < 2; _k++) \
        af[_m][_k] = *(const short8*)&smem[_ab + _m*1024 + kxo[_k]]; \
    } } while(0)

#define LOADB(_bf, _nh) do { \
    int _bb = ((_bf)*4 + 2 + (_nh))*8192 + (wc*32 + mrow)*64; \
    _Pragma("unroll") \
    for (int _n = 0; _n < 2; _n++) { \
      _Pragma("unroll") \
      for (int _k = 0; _k < 2; _k++) \
        bfr[_n][_k] = *(const short8*)&smem[_bb + _n*1024 + kxo[_k]]; \
    } } while(0)

#define MFMAQ(_mh, _nh) do { \
    _Pragma("unroll") \
    for (int _m = 0; _m < 4; _m++) \
      _Pragma("unroll") \
      for (int _n = 0; _n < 2; _n++) \
        _Pragma("unroll") \
        for (int _k = 0; _k < 2; _k++) \
          acc[(_mh)*4+_m][(_nh)*2+_n] = __builtin_amdgcn_mfma_f32_16x16x32_bf16( \
              af[_m][_k], bfr[_n][_k], acc[(_mh)*4+_m][(_nh)*2+_n], 0, 0, 0); \
    } while(0)

#define STAGE_A0(_nb) do { gl2lds16(pA00, &smem[((_nb)*4+0)*8192 + w*512]); \
                           gl2lds16(pA01, &smem[((_nb)*4+0)*8192 + 4096 + w*512]); \
                           pA00 += 64; pA01 += 64; } while(0)
#define STAGE_A1(_nb) do { gl2lds16(pA10, &smem[((_nb)*4+1)*8192 + w*512]); \
                           gl2lds16(pA11, &smem[((_nb)*4+1)*8192 + 4096 + w*512]); \
                           pA10 += 64; pA11 += 64; } while(0)
#define STAGE_B0(_nb) do { gl2lds16(pB00, &smem[((_nb)*4+2)*8192 + w*512]); \
                           gl2lds16(pB01, &smem[((_nb)*4+2)*8192 + 4096 + w*512]); \
                           pB00 += 64; pB01 += 64; } while(0)
#define STAGE_B1(_nb) do { gl2lds16(pB10, &smem[((_nb)*4+3)*8192 + w*512]); \
                           gl2lds16(pB11, &smem[((_nb)*4+3)*8192 + 4096 + w*512]); \
                           pB10 += 64; pB11 += 64; } while(0)

template<int MODE>
__global__ __launch_bounds__(512) void ffn_kernel(
    const bf16* __restrict__ Asrc,   // xb (MODE0) / hbuf (MODE1)
    const bf16* __restrict__ Bsrc1,  // w1t / w2t
    const bf16* __restrict__ Bsrc3,  // w3t / (unused)
    const void* __restrict__ bv1,    // b1 / b2
    const void* __restrict__ bv3,    // b3 / (unused)
    const int* __restrict__ dtf,
    const int* __restrict__ cnt, const int* __restrict__ offs,
    const int* __restrict__ idx_buf,
    bf16* __restrict__ Out)          // hbuf / outs
{
    const int KD = MODE ? Hm : Dm;
    const int NT = KD / 64;
    int e = blockIdx.z;
    int c = cnt[e];
    int m0 = blockIdx.y * 256;
    if (m0 >= c) return;
    int n0 = blockIdx.x * (MODE ? 256 : 128);
    int fp32 = *dtf;
    int slot0 = offs[e] + m0;

    __shared__ __align__(16) bf16 smem[65536];   // 128 KiB: [buf2][op2][half2][128][64]
    __shared__ int tk[256];

    int tid = threadIdx.x;
    int cm = c - 1 - m0; if (cm > 255) cm = 255;
    if (tid < 256) {
        int r = tid > cm ? cm : tid;
        int v = idx_buf[e*Ntok + m0 + r];
        tk[tid] = MODE ? (2*(v & 0xffff) + (v >> 16)) : (v & 0xffff);
    }
    __syncthreads();

    int lane = tid & 63, w = tid >> 6;
    int wr = w >> 2, wc = w & 3;
    int mrow = lane & 15, kg = lane >> 4;
    int flip = mrow & 7;
    int kxo[2];
    kxo[0] = ((0*4 + kg) ^ flip) * 8;
    kxo[1] = ((1*4 + kg) ^ flip) * 8;

    // staging geometry: thread covers rows {rs, 64+rs} of each half; 16B chunk cs_src
    int rs = tid >> 3;                       // 0..63
    int cs_src = (tid & 7) ^ (rs & 7);       // inverse swizzle on global source

    const bf16 *pA00, *pA01, *pA10, *pA11, *pB00, *pB01, *pB10, *pB11;
    {
        int r00 = rs, r01 = 64 + rs, r10 = 128 + rs, r11 = 192 + rs;
        if (MODE == 0) {
            pA00 = Asrc + (size_t)tk[r00] * Dm + cs_src*8;
            pA01 = Asrc + (size_t)tk[r01] * Dm + cs_src*8;
            pA10 = Asrc + (size_t)tk[r10] * Dm + cs_src*8;
            pA11 = Asrc + (size_t)tk[r11] * Dm + cs_src*8;
        } else {
            int c00 = r00 > cm ? cm : r00, c01 = r01 > cm ? cm : r01;
            int c10 = r10 > cm ? cm : r10, c11 = r11 > cm ? cm : r11;
            pA00 = Asrc + (size_t)(slot0 + c00) * Hm + cs_src*8;
            pA01 = Asrc + (size_t)(slot0 + c01) * Hm + cs_src*8;
            pA10 = Asrc + (size_t)(slot0 + c10) * Hm + cs_src*8;
            pA11 = Asrc + (size_t)(slot0 + c11) * Hm + cs_src*8;
        }
        if (MODE == 0) {
            #pragma unroll
            for (int hl = 0; hl < 4; hl++) {
                int r = hl*64 + rs;
                int matb = (r >> 4) & 1;
                int hcol = n0 + (r >> 7)*64 + ((r >> 5) & 3)*16 + (r & 15);
                const bf16* base = (matb ? Bsrc3 : Bsrc1) + (size_t)e*Hm*Dm
                                 + (size_t)hcol * Dm + cs_src*8;
                if (hl == 0) pB00 = base; else if (hl == 1) pB01 = base;
                else if (hl == 2) pB10 = base; else pB11 = base;
            }
        } else {
            pB00 = Bsrc1 + (size_t)e*Dm*Hm + (size_t)(n0 + rs      ) * Hm + cs_src*8;
            pB01 = Bsrc1 + (size_t)e*Dm*Hm + (size_t)(n0 + rs +  64) * Hm + cs_src*8;
            pB10 = Bsrc1 + (size_t)e*Dm*Hm + (size_t)(n0 + rs + 128) * Hm + cs_src*8;
            pB11 = Bsrc1 + (size_t)e*Dm*Hm + (size_t)(n0 + rs + 192) * Hm + cs_src*8;
        }
    }

    f32x4 acc[8][4];
    f32x4 z = {0.f, 0.f, 0.f, 0.f};
    #pragma unroll
    for (int m = 0; m < 8; m++)
        #pragma unroll
        for (int n = 0; n < 4; n++) acc[m][n] = z;

    short8 af[4][2];
    short8 bfr[2][2];

    // prologue: stage K-tile 0 into buf 0, drain, sync
    STAGE_A0(0); STAGE_B0(0); STAGE_B1(0); STAGE_A1(0);
    VMW0();
    __syncthreads();

    for (int t = 0; t < NT; ++t) {
        int buf = t & 1, nbuf = buf ^ 1;
        bool more = (t + 1 < NT);
        // ---- q0: quadrant (mh0, nh0) ----
        LOADA(buf, 0); LOADB(buf, 0);
        if (more) STAGE_A0(nbuf);
        BAR();
        __builtin_amdgcn_s_setprio(1); MFMAQ(0, 0); __builtin_amdgcn_s_setprio(0);
        if (more) VMW4(); else VMW2();
        BAR();
        // ---- q1: (mh0, nh1) — af kept, read B1 ----
        LOADB(buf, 1);
        if (more) STAGE_B0(nbuf);
        BAR();
        __builtin_amdgcn_s_setprio(1); MFMAQ(0, 1); __builtin_amdgcn_s_setprio(0);
        if (more) VMW4(); else VMW0();
        BAR();
        // ---- q2: (mh1, nh1) — bfr kept, read A1 ----
        LOADA(buf, 1);
        if (more) STAGE_B1(nbuf);
        BAR();
        __builtin_amdgcn_s_setprio(1); MFMAQ(1, 1); __builtin_amdgcn_s_setprio(0);
        BAR();
        // ---- q3: (mh1, nh0) — af kept, re-read B0 (landed long ago) ----
        LOADB(buf, 0);
        if (more) STAGE_A1(nbuf);
        BAR();
        __builtin_amdgcn_s_setprio(1); MFMAQ(1, 0); __builtin_amdgcn_s_setprio(0);
        if (more) VMW4();
        BAR();
    }

    // ---- epilogue ----
    if (MODE == 0) {
        #pragma unroll
        for (int nh = 0; nh < 2; nh++) {
            int hcol = n0 + nh*64 + wc*16 + mrow;
            float bb1 = fp32 ? ((const float*)bv1)[e*Hm + hcol] : b2f(((const bf16*)bv1)[e*Hm + hcol]);
            float bb3 = fp32 ? ((const float*)bv3)[e*Hm + hcol] : b2f(((const bf16*)bv3)[e*Hm + hcol]);
            #pragma unroll
            for (int ms = 0; ms < 8; ms++) {
                int rbase = (ms>>2)*128 + wr*64 + (ms&3)*16 + kg*4;
                #pragma unroll
                for (int j = 0; j < 4; j++) {
                    int tr = rbase + j;
                    if (m0 + tr < c) {
                        float v1 = acc[ms][nh*2+0][j] + bb1;
                        float v3 = acc[ms][nh*2+1][j] + bb3;
                        float hv = (v1 / (1.f + expf(-v1))) * v3;   // silu(v1)*v3
                        Out[(size_t)(slot0 + tr)*Hm + hcol] = f2b(hv);
                    }
                }
            }
        }
    } else {
        #pragma unroll
        for (int ns = 0; ns < 4; ns++) {
            int col = n0 + (ns>>1)*128 + wc*32 + (ns&1)*16 + mrow;
            float bb2 = fp32 ? ((const float*)bv1)[e*Dm + col] : b2f(((const bf16*)bv1)[e*Dm + col]);
            #pragma unroll
            for (int ms = 0; ms < 8; ms++) {
                int rbase = (ms>>2)*128 + wr*64 + (ms&3)*16 + kg*4;
                #pragma unroll
                for (int j = 0; j < 4; j++) {
                    int tr = rbase + j;
                    if (m0 + tr < c)
                        Out[(size_t)tk[tr]*Dm + col] = f2b(acc[ms][ns][j] + bb2);
                }
            }
        }
    }
}

#undef LOADA
#undef LOADB
#undef MFMAQ
#undef STAGE_A0
#undef STAGE_A1
#undef STAGE_B0
#undef STAGE_B1

// ---------------- combine: y[n] = w0*out[2n] + w1*out[2n+1] ----------------
__global__ void combine_kernel(const bf16* __restrict__ outs, const float* __restrict__ wts,
                               const int* __restrict__ dtf, void* __restrict__ yv)
{
    int gid = blockIdx.x * 256 + threadIdx.x;
    int n = gid >> 7;
    int j = (gid & 127) * 8;
    float w0 = wts[2*n], w1 = wts[2*n+1];
    bf16 ra[8], rb[8];
    *(uint4*)ra = *(const uint4*)(outs + (size_t)(2*n)   * Dm + j);
    *(uint4*)rb = *(const uint4*)(outs + (size_t)(2*n+1) * Dm + j);
    float o[8];
    #pragma unroll
    for (int t = 0; t < 8; t++)
        o[t] = w0 * b2f(ra[t]) + w1 * b2f(rb[t]);
    if (*dtf) {
        float* y = (float*)yv + (size_t)n * Dm + j;
        *(float4*)y       = make_float4(o[0], o[1], o[2], o[3]);
        *(float4*)(y + 4) = make_float4(o[4], o[5], o[6], o[7]);
    } else {
        bf16 ro[8];
        #pragma unroll
        for (int t = 0; t < 8; t++) ro[t] = f2b(o[t]);
        *(uint4*)((bf16*)yv + (size_t)n * Dm + j) = *(uint4*)ro;
    }
}

extern "C" void kernel_launch(void* const* d_in, const int* in_sizes, int n_in,
                              void* d_out, int out_size, void* d_ws, size_t ws_size,
                              hipStream_t stream)
{
    (void)in_sizes; (void)n_in; (void)out_size; (void)ws_size;
    const void* x  = d_in[0];
    const void* Wg = d_in[1];
    const void* W1 = d_in[2];
    const void* b1 = d_in[3];
    const void* W2 = d_in[4];
    const void* b2 = d_in[5];
    const void* W3 = d_in[6];
    const void* b3 = d_in[7];

    char* ws = (char*)d_ws;
    int*   cnt  = (int*)ws;                      // [0,32)
    int*   dtf  = (int*)(ws + 64);               // dtype flag
    int*   offs = (int*)(ws + 512);              // [512,544)
    float* Psum = (float*)(ws + 1024);           // [1024,1536), stride 16 floats (64B/expert)
    float* wts  = (float*)(ws + 4096);           // 64 KB -> 69632
    int*   idx  = (int*)(ws + 69632);            // 256 KB -> 331776
    bf16* bufA  = (bf16*)(ws + 331776);          // 32 MiB (w1t, then w2t)
    bf16* bufB  = (bf16*)(ws + 33886208);        // 32 MiB (w3t, then outs)
    bf16* hbuf  = (bf16*)(ws + 67440640);        // 64 MiB
    bf16* outs  = bufB;
    bf16* xb    = (bf16*)d_out;                  // x as bf16 in d_out scratch (dead before combine)

    hipMemsetAsync(d_ws, 0, 4096, stream);
    detect_kernel<<<1, 64, 0, stream>>>((const unsigned*)x, dtf);
    // gate fuses x->bf16 conversion (writes xb) with routing
    gate_kernel<<<Ntok/16, 1024, 0, stream>>>(x, Wg, dtf, cnt, Psum, wts, idx, xb);
    aux_kernel<<<1, 64, 0, stream>>>(cnt, Psum, dtf, offs, d_out);
    // W1,W3: [D][H] -> [H][D]
    transpose2_kernel<<<dim3(Hm/64, Dm/64, 16), 256, 0, stream>>>(W1, W3, bufA, bufB, Dm, Hm, dtf);
    ffn_kernel<0><<<dim3(Hm/128, Ntok/256, NE), 512, 0, stream>>>(
        xb, bufA, bufB, b1, b3, dtf, cnt, offs, idx, hbuf);
    // W2: [H][D] -> [D][H]  (into bufA, w1t dead)
    transpose2_kernel<<<dim3(Dm/64, Hm/64, 8), 256, 0, stream>>>(W2, W2, bufA, bufA, Hm, Dm, dtf);
    ffn_kernel<1><<<dim3(Dm/256, Ntok/256, NE), 512, 0, stream>>>(
        hbuf, bufA, bufA, b2, b2, dtf, cnt, offs, idx, outs);
    combine_kernel<<<(Ntok*Dm/8)/256, 256, 0, stream>>>(outs, wts, dtf, d_out);
}